// Round 7
// baseline (568.032 us; speedup 1.0000x reference)
//
#include <hip/hip_runtime.h>
#include <math.h>

#define B_   16
#define D_   128
#define N_   8192
#define EPS_ 1e-5f
#define SCALE_ 0.08838834764831845f   // 128^-0.5
#define NEG_ -3.4028235e38f

typedef _Float16 half8 __attribute__((ext_vector_type(8)));
typedef _Float16 half4 __attribute__((ext_vector_type(4)));
typedef float f32x16 __attribute__((ext_vector_type(16)));
#define MFMA32(a,b,c) __builtin_amdgcn_mfma_f32_32x32x16_f16(a,b,c,0,0,0)

// Workspace layout (float offsets). High-water ~190 MB.
#define OFF_QA    0UL          // q (B,N,D) f16; aliased as attention output a
#define OFF_K     8388608UL    // k (B,N,D) f16 (pre-rotary)
#define OFF_VT    16777216UL   // v transposed (B,D,N) f16
#define OFF_AT    25165824UL   // a transposed (B,D,N) f16
#define OFF_XT    33554432UL   // x transposed (B,N,132) f16, row-padded
#define OFF_ROPE  42205184UL   // N x 64 pairs (cos,sin) f32
#define OFF_WB    43253760UL   // prepacked conv weights f16 [c*5+t][o][132]
#define OFF_INVF  43380480UL   // 64 f32
#define OFF_W2H   43380544UL   // 128x128 f16 folded 1x1 weights
#define OFF_B2    43388736UL   // 128 f32
#define OFF_MEANP 43388864UL   // 256 x 128 partial colsums
#define OFF_SP    43421632UL   // 256 x 16384 partial S
#define OFF_MEAN  47615936UL   // 128
#define OFF_S     47616064UL   // 16384

// XOR-swizzled LDS index (stride 128 halfs) — used by attention only.
__device__ __forceinline__ int swz(int row, int col) {
  return row * 128 + ((((col >> 3) ^ (row & 7))) << 3) + (col & 7);
}

// ---------------------------------------------------------------------------
__global__ __launch_bounds__(64) void invf_kernel(float* __restrict__ invf) {
  int j = threadIdx.x;
  invf[j] = (float)pow(10000.0, -(double)j / 64.0);
}

__global__ __launch_bounds__(256) void rope2_kernel(const float* __restrict__ invf,
                                                    float* __restrict__ rope2) {
  int idx = blockIdx.x * 256 + threadIdx.x;   // n*64 + j
  int n = idx >> 6, j = idx & 63;
  float ph = (float)n * invf[j];              // fp32 like jax
  rope2[(size_t)n * 128 + 2 * j]     = cosf(ph);
  rope2[(size_t)n * 128 + 2 * j + 1] = sinf(ph);
}

// Prepacked conv weights, row-padded to 132 halfs: WB[ct][o][i], q pre-scaled.
__global__ __launch_bounds__(128) void prepack_kernel(
    const float* __restrict__ qw, const float* __restrict__ kw,
    const float* __restrict__ vw, _Float16* __restrict__ WB) {
  int o = blockIdx.x, t = blockIdx.y, c = blockIdx.z, i = threadIdx.x;
  const float* w = (c == 0) ? qw : (c == 1) ? kw : vw;
  float v = w[(o * 128 + i) * 5 + t] * (c == 0 ? SCALE_ : 1.f);
  WB[((size_t)(c * 5 + t) * 128 + o) * 132 + i] = (_Float16)v;
}

// ---------------------------------------------------------------------------
// Transpose x (B,D,N) f32 -> xT (B,N,132) f16 (128 data halfs + 4 pad/row).
// ---------------------------------------------------------------------------
__global__ __launch_bounds__(256) void xpose_kernel(
    const float* __restrict__ x, _Float16* __restrict__ xT)
{
  __shared__ _Float16 ls[64 * 132];
  const int b = blockIdx.y, n0 = blockIdx.x * 64;
  const int tid = threadIdx.x;
  {
    const int q = tid & 3;
    #pragma unroll
    for (int pass = 0; pass < 2; ++pass) {
      int d = (tid >> 2) + pass * 64;
      const float* src = x + ((size_t)b * 128 + d) * (size_t)N_ + n0;
      #pragma unroll
      for (int m = 0; m < 4; ++m) {
        int p = m * 16 + q * 4;
        float4 v = *(const float4*)(src + p);
        ls[(p + 0) * 132 + d] = (_Float16)v.x;
        ls[(p + 1) * 132 + d] = (_Float16)v.y;
        ls[(p + 2) * 132 + d] = (_Float16)v.z;
        ls[(p + 3) * 132 + d] = (_Float16)v.w;
      }
    }
  }
  __syncthreads();
  {
    const int p = tid >> 2, c4 = tid & 3;
    _Float16* dst = xT + ((size_t)b * N_ + n0 + p) * 132;
    #pragma unroll
    for (int mm = 0; mm < 8; ++mm) {
      int cc = (c4 + mm * 4) * 4;   // halfs offset, 32 chunks of 4 halfs
      *(half4*)(dst + cc) = *(const half4*)(ls + p * 132 + cc);
    }
  }
}

// ---------------------------------------------------------------------------
// Fused q/k/v causal conv as 5 shifted K=128 f16 GEMMs (32x32x16 MFMA).
// 512 thr (8 waves), 256 positions x 128 outputs per block. Double-buffered
// weights (reg-stage early / ds-write late), 1 barrier per tap. Conflict-free
// LDS strides (132 halfs = 66 words == 2 mod 32).
// ---------------------------------------------------------------------------
__global__ __launch_bounds__(512, 2) void conv_kernel(
    const _Float16* __restrict__ xT, const _Float16* __restrict__ WB,
    const float* __restrict__ qb, const float* __restrict__ kb_,
    const float* __restrict__ vb,
    _Float16* __restrict__ qo, _Float16* __restrict__ ko,
    _Float16* __restrict__ vT)
{
  __shared__ _Float16 xs[260 * 132];        // 68640 B: rows = pos (4 halo)
  __shared__ _Float16 wbuf[2][128 * 132];   // 2 x 33792 B
  const int b = blockIdx.y, n0 = blockIdx.x * 256;
  const int tid = threadIdx.x;
  const int lane = tid & 63, wq = tid >> 6;
  const int l31 = lane & 31, h = lane >> 5;

  // ---- prologue: linear copy xs tile + weight tap 0
  {
    const _Float16* src = xT + ((size_t)b * N_ + n0 - 4) * 132;  // 16B-aligned
    #pragma unroll
    for (int kk = 0; kk < 9; ++kk) {
      int u = kk * 512 + tid;
      if (u < 4290) *(half8*)(xs + u * 8) = *(const half8*)(src + u * 8);
    }
    #pragma unroll
    for (int kk = 0; kk < 5; ++kk) {
      int u = kk * 512 + tid;
      if (u < 2112) *(half8*)(&wbuf[0][0] + u * 8) = *(const half8*)(WB + u * 8);
    }
  }
  __syncthreads();
  if (n0 == 0) {   // zero the 4 halo rows (x[-4..-1])
    xs[tid] = (_Float16)0.f;
    if (tid < 16) xs[512 + tid] = (_Float16)0.f;
  }
  __syncthreads();

  int rowof[16];
  #pragma unroll
  for (int r = 0; r < 16; ++r) rowof[r] = (r & 3) + 8 * (r >> 2) + 4 * h;

  f32x16 acc[4];
  #pragma unroll
  for (int nt = 0; nt < 4; ++nt)
    #pragma unroll
    for (int u = 0; u < 16; ++u) acc[nt][u] = 0.f;

  for (int c = 0; c < 3; ++c) {
    for (int t = 0; t < 5; ++t) {
      const int ct = c * 5 + t;
      const int cur = ct & 1;
      const bool more = ct < 14;
      half8 wreg[5];
      if (more) {   // issue next tap's weight loads early (latency hides)
        const _Float16* wsrc = WB + (size_t)(ct + 1) * 16896;
        #pragma unroll
        for (int kk = 0; kk < 5; ++kk) {
          int u = kk * 512 + tid;
          if (u < 2112) wreg[kk] = *(const half8*)(wsrc + u * 8);
        }
      }
      // MFMAs for this tap
      const int abase = (wq * 32 + l31 + t) * 132;
      const _Float16* wb_ = &wbuf[cur][0];
      #pragma unroll
      for (int kb2 = 0; kb2 < 8; ++kb2) {
        half8 av = *(const half8*)(xs + abase + (kb2 * 2 + h) * 8);
        #pragma unroll
        for (int nt = 0; nt < 4; ++nt) {
          int o = nt * 32 + l31;
          half8 bv = *(const half8*)(wb_ + o * 132 + (kb2 * 2 + h) * 8);
          acc[nt] = MFMA32(av, bv, acc[nt]);
        }
      }
      if (more) {   // write-late into the other buffer (not in use)
        _Float16* wdst = &wbuf[cur ^ 1][0];
        #pragma unroll
        for (int kk = 0; kk < 5; ++kk) {
          int u = kk * 512 + tid;
          if (u < 2112) *(half8*)(wdst + u * 8) = wreg[kk];
        }
      }
      if (t == 4 && c < 2) {   // q/k epilogue: rope deferred to attn
        const float* bias = (c == 0) ? qb : kb_;
        const float bsc = (c == 0) ? SCALE_ : 1.f;
        _Float16* outp = (c == 0) ? qo : ko;
        #pragma unroll
        for (int nt = 0; nt < 4; ++nt) {
          int o = nt * 32 + l31;
          float bv = bias[o] * bsc;
          #pragma unroll
          for (int r = 0; r < 16; ++r) {
            int pos = wq * 32 + rowof[r];
            outp[((size_t)b * N_ + n0 + pos) * 128 + o] = (_Float16)(acc[nt][r] + bv);
          }
          #pragma unroll
          for (int r = 0; r < 16; ++r) acc[nt][r] = 0.f;
        }
      }
      __syncthreads();
    }
  }

  // ---- v epilogue: transpose via xs reuse (stride 260 halfs), -> vT (B,D,N)
  {
    _Float16* vbuf = xs;
    #pragma unroll
    for (int nt = 0; nt < 4; ++nt) {
      int o = nt * 32 + l31;
      float bv = vb[o];
      #pragma unroll
      for (int r = 0; r < 16; ++r) {
        int pos = wq * 32 + rowof[r];
        vbuf[o * 260 + pos] = (_Float16)(acc[nt][r] + bv);
      }
    }
    __syncthreads();
    const int o2 = tid & 127, seg = tid >> 7;
    _Float16* dst = vT + ((size_t)b * 128 + o2) * (size_t)N_ + n0 + seg * 64;
    #pragma unroll
    for (int m = 0; m < 16; ++m)
      *(half4*)(dst + m * 4) = *(const half4*)(vbuf + o2 * 260 + seg * 64 + m * 4);
  }
}

// ---------------------------------------------------------------------------
// Local causal attention, f16 MFMA, flash-style over 2 key chunks.
// Writes a (B,N,D) [aliases q] AND aT (B,D,N) via q_s LDS bounce.
// ---------------------------------------------------------------------------
__device__ __forceinline__ void stage_rot(const _Float16* __restrict__ src_base,
                                          _Float16* __restrict__ dst,
                                          const float* __restrict__ rope2,
                                          int nbase, int tid)
{
  int row = tid >> 2, p = tid & 3;
  const _Float16* src = src_base + (size_t)row * 128;
  const float* rp = rope2 + ((size_t)(nbase + row)) * 128 + p * 32;
  half8 lo0 = *(const half8*)(src + p * 16);
  half8 lo1 = *(const half8*)(src + p * 16 + 8);
  half8 hi0 = *(const half8*)(src + 64 + p * 16);
  half8 hi1 = *(const half8*)(src + 64 + p * 16 + 8);
  half8 olo0, olo1, ohi0, ohi1;
  #pragma unroll
  for (int u = 0; u < 8; ++u) {
    float c0 = rp[2 * u], s0 = rp[2 * u + 1];
    float c1 = rp[16 + 2 * u], s1 = rp[16 + 2 * u + 1];
    float xl0 = (float)lo0[u], xh0 = (float)hi0[u];
    float xl1 = (float)lo1[u], xh1 = (float)hi1[u];
    olo0[u] = (_Float16)(xl0 * c0 - xh0 * s0);
    ohi0[u] = (_Float16)(xh0 * c0 + xl0 * s0);
    olo1[u] = (_Float16)(xl1 * c1 - xh1 * s1);
    ohi1[u] = (_Float16)(xh1 * c1 + xl1 * s1);
  }
  int r7 = row & 7;
  *(half8*)(dst + row * 128 + (((p * 2)     ^ r7) << 3)) = olo0;
  *(half8*)(dst + row * 128 + (((p * 2 + 1) ^ r7) << 3)) = olo1;
  *(half8*)(dst + row * 128 + (((8 + p * 2) ^ r7) << 3)) = ohi0;
  *(half8*)(dst + row * 128 + (((9 + p * 2) ^ r7) << 3)) = ohi1;
}

__device__ __forceinline__ void stage_vT(const _Float16* __restrict__ vsrc,
                                         _Float16* __restrict__ dst, int tid)
{
  int d = tid >> 2, p = tid & 3;
  const _Float16* src = vsrc + (size_t)d * (size_t)N_;
  int r7 = d & 7;
  #pragma unroll
  for (int m = 0; m < 4; ++m) {
    int kp = m * 32 + p * 8;
    half8 v = *(const half8*)(src + kp);
    *(half8*)(dst + d * 128 + ((((kp >> 3) ^ r7)) << 3)) = v;
  }
}

__global__ __launch_bounds__(512, 2) void attn_kernel(
    const _Float16* __restrict__ q, const _Float16* __restrict__ k,
    const _Float16* __restrict__ vT, const float* __restrict__ rope2,
    _Float16* __restrict__ aout, _Float16* __restrict__ aTout)
{
  __shared__ _Float16 q_s[128 * 128];
  __shared__ _Float16 k_s[128 * 128];
  __shared__ _Float16 vT_s[128 * 128];
  __shared__ _Float16 P_s[128 * 128];
  __shared__ float red_m[2][128];
  __shared__ float red_s[2][128];

  const int b = blockIdx.y, w = blockIdx.x;
  const int tid = threadIdx.x, lane = tid & 63, wid = tid >> 6;
  const int wr = wid >> 1, wc = wid & 1;
  const int l31 = lane & 31, h = lane >> 5;

  stage_rot(q + ((size_t)b * N_ + w * 128) * 128, q_s, rope2, w * 128, tid);

  float mrun[16], lrun[16];
  f32x16 O[2];
  #pragma unroll
  for (int r = 0; r < 16; ++r) { mrun[r] = NEG_; lrun[r] = 0.f; O[0][r] = 0.f; O[1][r] = 0.f; }

  const int qrow = wr * 32 + l31;
  const int r7q = qrow & 7;
  int rowof[16];
  #pragma unroll
  for (int r = 0; r < 16; ++r) rowof[r] = wr * 32 + (r & 3) + 8 * (r >> 2) + 4 * h;

  for (int ch = (w == 0 ? 1 : 0); ch < 2; ++ch) {
    int kv0 = w * 128 - 128 + ch * 128;
    __syncthreads();   // protect k_s/vT_s vs prev PV; covers q_s staging on 1st iter
    stage_rot(k + ((size_t)b * N_ + kv0) * 128, k_s, rope2, kv0, tid);
    stage_vT(vT + (size_t)b * 128 * (size_t)N_ + kv0, vT_s, tid);
    __syncthreads();

    // QK^T
    f32x16 sim[2];
    #pragma unroll
    for (int r = 0; r < 16; ++r) { sim[0][r] = 0.f; sim[1][r] = 0.f; }
    #pragma unroll
    for (int kb2 = 0; kb2 < 8; ++kb2) {
      half8 av = *(const half8*)(q_s + qrow * 128 + ((((kb2 * 2 + h) ^ r7q)) << 3));
      #pragma unroll
      for (int nt = 0; nt < 2; ++nt) {
        int krow = wc * 64 + nt * 32 + l31;
        half8 bv = *(const half8*)(k_s + krow * 128 + ((((kb2 * 2 + h) ^ (krow & 7))) << 3));
        sim[nt] = MFMA32(av, bv, sim[nt]);
      }
    }
    if (ch == 1) {  // causal mask within current window
      #pragma unroll
      for (int nt = 0; nt < 2; ++nt) {
        int col = wc * 64 + nt * 32 + l31;
        #pragma unroll
        for (int r = 0; r < 16; ++r)
          if (col > rowof[r]) sim[nt][r] = NEG_;
      }
    }

    // row max (this wave's 64 cols)
    float pm[16];
    #pragma unroll
    for (int r = 0; r < 16; ++r) pm[r] = fmaxf(sim[0][r], sim[1][r]);
    #pragma unroll
    for (int m = 1; m <= 16; m <<= 1)
      #pragma unroll
      for (int r = 0; r < 16; ++r) pm[r] = fmaxf(pm[r], __shfl_xor(pm[r], m));
    if (l31 == 0) {
      #pragma unroll
      for (int r = 0; r < 16; ++r) red_m[wc][rowof[r]] = pm[r];
    }
    __syncthreads();

    float scale[16], ps[16];
    #pragma unroll
    for (int r = 0; r < 16; ++r) {
      float mc = fmaxf(red_m[0][rowof[r]], red_m[1][rowof[r]]);
      float mn = fmaxf(mrun[r], mc);
      scale[r] = __expf(mrun[r] - mn);
      mrun[r] = mn;
      ps[r] = 0.f;
    }
    #pragma unroll
    for (int nt = 0; nt < 2; ++nt) {
      int col = wc * 64 + nt * 32 + l31;
      #pragma unroll
      for (int r = 0; r < 16; ++r) {
        float p = __expf(sim[nt][r] - mrun[r]);
        ps[r] += p;
        P_s[swz(rowof[r], col)] = (_Float16)p;
      }
    }
    #pragma unroll
    for (int m = 1; m <= 16; m <<= 1)
      #pragma unroll
      for (int r = 0; r < 16; ++r) ps[r] += __shfl_xor(ps[r], m);
    if (l31 == 0) {
      #pragma unroll
      for (int r = 0; r < 16; ++r) red_s[wc][rowof[r]] = ps[r];
    }
    __syncthreads();

    #pragma unroll
    for (int r = 0; r < 16; ++r) {
      float ss = red_s[0][rowof[r]] + red_s[1][rowof[r]];
      lrun[r] = lrun[r] * scale[r] + ss;
      O[0][r] *= scale[r];
      O[1][r] *= scale[r];
    }

    // PV
    #pragma unroll
    for (int kb2 = 0; kb2 < 8; ++kb2) {
      half8 pa = *(const half8*)(P_s + qrow * 128 + ((((kb2 * 2 + h) ^ r7q)) << 3));
      #pragma unroll
      for (int nt = 0; nt < 2; ++nt) {
        int drow = wc * 64 + nt * 32 + l31;
        half8 bv = *(const half8*)(vT_s + drow * 128 + ((((kb2 * 2 + h) ^ (drow & 7))) << 3));
        O[nt] = MFMA32(pa, bv, O[nt]);
      }
    }
  }

  // epilogue: normalize, store a (B,N,D) f16 and stage transposed tile in q_s
  #pragma unroll
  for (int nt = 0; nt < 2; ++nt) {
    int col = wc * 64 + nt * 32 + l31;
    #pragma unroll
    for (int r = 0; r < 16; ++r) {
      float inv = 1.f / lrun[r];
      _Float16 val = (_Float16)(O[nt][r] * inv);
      aout[((size_t)b * N_ + w * 128 + rowof[r]) * 128 + col] = val;
      q_s[swz(col, rowof[r])] = val;
    }
  }
  __syncthreads();
  { // coalesced copy q_s -> aT (B,D,N)
    int d = tid >> 2, part = tid & 3;
    _Float16* dst = aTout + ((size_t)b * 128 + d) * (size_t)N_ + w * 128 + part * 32;
    #pragma unroll
    for (int mm = 0; mm < 4; ++mm) {
      int mb = part * 4 + mm;
      *(half8*)(dst + mm * 8) = *(const half8*)(q_s + d * 128 + ((mb ^ (d & 7)) << 3));
    }
  }
}

// ---------------------------------------------------------------------------
// BN stats via MFMA: partial S = a^T a and colsum from aT (B,D,N).
// ---------------------------------------------------------------------------
__global__ __launch_bounds__(256, 2) void stats_kernel(
    const _Float16* __restrict__ aT, float* __restrict__ Sp, float* __restrict__ meanp)
{
  __shared__ _Float16 ts[128 * 64];   // [chan][pos] swizzled, 16 KB
  const int bk = blockIdx.x;
  const int b = bk >> 4;
  const int nbase = (bk & 15) * 512;
  const int tid = threadIdx.x, lane = tid & 63, wv = tid >> 6;
  const int l31 = lane & 31, h = lane >> 5;

  f32x16 acc[4];
  #pragma unroll
  for (int jt = 0; jt < 4; ++jt)
    #pragma unroll
    for (int u = 0; u < 16; ++u) acc[jt][u] = 0.f;
  float csum = 0.f;

  const int i2 = tid >> 1, part = tid & 1;
  const int ia = wv * 32 + l31;
  for (int sc = 0; sc < 8; ++sc) {
    __syncthreads();
    {
      const _Float16* src = aT + ((size_t)b * 128 + i2) * (size_t)N_ + nbase + sc * 64 + part * 32;
      #pragma unroll
      for (int mm = 0; mm < 4; ++mm) {
        half8 v = *(const half8*)(src + mm * 8);
        int mb = part * 4 + mm;
        *(half8*)(ts + i2 * 64 + (((mb ^ (i2 & 7))) << 3)) = v;
      }
    }
    __syncthreads();
    if (tid < 128) {  // per-channel sum (order-independent)
      #pragma unroll
      for (int mb = 0; mb < 8; ++mb) {
        half8 v = *(const half8*)(ts + tid * 64 + (((mb ^ (tid & 7))) << 3));
        #pragma unroll
        for (int u = 0; u < 8; ++u) csum += (float)v[u];
      }
    }
    #pragma unroll
    for (int kk = 0; kk < 4; ++kk) {
      int mb = kk * 2 + h;
      half8 av = *(const half8*)(ts + ia * 64 + (((mb ^ (ia & 7))) << 3));
      #pragma unroll
      for (int jt = 0; jt < 4; ++jt) {
        int jb = jt * 32 + l31;
        half8 bvv = *(const half8*)(ts + jb * 64 + (((mb ^ (jb & 7))) << 3));
        acc[jt] = MFMA32(av, bvv, acc[jt]);
      }
    }
  }
  float* dst = Sp + (size_t)bk * 16384;
  #pragma unroll
  for (int jt = 0; jt < 4; ++jt)
    #pragma unroll
    for (int r = 0; r < 16; ++r) {
      int i = wv * 32 + (r & 3) + 8 * (r >> 2) + 4 * h;
      dst[i * 128 + jt * 32 + l31] = acc[jt][r];   // S symmetric: i/j swap safe
    }
  if (tid < 128) meanp[bk * 128 + tid] = csum;
}

__global__ __launch_bounds__(256) void reduce_kernel(
    const float* __restrict__ Sp, const float* __restrict__ meanp,
    float* __restrict__ S, float* __restrict__ mean)
{
  const int e = blockIdx.x * 256 + threadIdx.x;
  float s = 0.f;
  for (int bk = 0; bk < 256; ++bk) s += Sp[(size_t)bk * 16384 + e];
  S[e] = s;
  if (blockIdx.x == 0 && threadIdx.x < 128) {
    float ms = 0.f;
    for (int bk = 0; bk < 256; ++bk) ms += meanp[bk * 128 + threadIdx.x];
    mean[threadIdx.x] = ms * (1.f / (float)(B_ * N_));
  }
}

// ---------------------------------------------------------------------------
// BN fold, parallel: 128 blocks (one per output channel) x 128 threads.
// ---------------------------------------------------------------------------
__global__ __launch_bounds__(128) void fold_kernel(
    const float* __restrict__ S, const float* __restrict__ mean,
    const float* __restrict__ ow, const float* __restrict__ gamma,
    const float* __restrict__ beta,
    _Float16* __restrict__ w2h, float* __restrict__ b2)
{
  __shared__ float wo_s[128];
  __shared__ float qred[2], dred[2];
  const int o = blockIdx.x, i = threadIdx.x;
  const int lane = i & 63, wv = i >> 6;
  float wi = ow[o * 128 + i];
  wo_s[i] = wi;
  __syncthreads();
  const float* Srow = S + i * 128;
  float t = 0.f;
  #pragma unroll 8
  for (int j = 0; j < 128; ++j) t = fmaf(Srow[j], wo_s[j], t);
  float quad = wi * t;
  float dm = wi * mean[i];
  #pragma unroll
  for (int m = 1; m <= 32; m <<= 1) {
    quad += __shfl_xor(quad, m);
    dm   += __shfl_xor(dm, m);
  }
  if (lane == 0) { qred[wv] = quad; dred[wv] = dm; }
  __syncthreads();
  float quadT = qred[0] + qred[1];
  float dmT   = dred[0] + dred[1];
  float var = quadT * (1.f / (float)(B_ * N_)) - dmT * dmT;
  var = fmaxf(var, 0.f);
  float sc = gamma[o] * rsqrtf(var + EPS_);
  if (i == 0) b2[o] = beta[o] - sc * dmT;   // o_b cancels against mean_y
  w2h[o * 128 + i] = (_Float16)(sc * wi);
}

// ---------------------------------------------------------------------------
// Final 1x1 conv via MFMA: A=w2h (o rows), B=a (pos rows) -> D col=pos
// ---------------------------------------------------------------------------
__global__ __launch_bounds__(256, 2) void out_kernel(
    const _Float16* __restrict__ a, const _Float16* __restrict__ w2h,
    const float* __restrict__ b2, float* __restrict__ out)
{
  __shared__ _Float16 a_s[128 * 128];
  __shared__ _Float16 w_s[128 * 128];
  const int b = blockIdx.y, n0 = blockIdx.x * 128;
  const int tid = threadIdx.x, lane = tid & 63, wv = tid >> 6;
  const int l31 = lane & 31, h = lane >> 5;
  {
    int row = tid >> 1, part = tid & 1;
    const _Float16* asrc = a + ((size_t)b * N_ + n0 + row) * 128 + part * 64;
    const _Float16* wsrc = w2h + row * 128 + part * 64;
    #pragma unroll
    for (int mm = 0; mm < 8; ++mm) {
      int mb = part * 8 + mm;
      int off = row * 128 + ((mb ^ (row & 7)) << 3);
      *(half8*)(a_s + off) = *(const half8*)(asrc + mm * 8);
      *(half8*)(w_s + off) = *(const half8*)(wsrc + mm * 8);
    }
  }
  __syncthreads();
  f32x16 acc[4];
  #pragma unroll
  for (int pt = 0; pt < 4; ++pt)
    #pragma unroll
    for (int u = 0; u < 16; ++u) acc[pt][u] = 0.f;
  const int orow = wv * 32 + l31;
  #pragma unroll
  for (int kk = 0; kk < 8; ++kk) {
    int mb = kk * 2 + h;
    half8 av = *(const half8*)(w_s + orow * 128 + ((mb ^ (orow & 7)) << 3));
    #pragma unroll
    for (int pt = 0; pt < 4; ++pt) {
      int prow = pt * 32 + l31;
      half8 bvv = *(const half8*)(a_s + prow * 128 + ((mb ^ (prow & 7)) << 3));
      acc[pt] = MFMA32(av, bvv, acc[pt]);
    }
  }
  float bias[16];
  int orows[16];
  #pragma unroll
  for (int r = 0; r < 16; ++r) {
    orows[r] = wv * 32 + (r & 3) + 8 * (r >> 2) + 4 * h;
    bias[r] = b2[orows[r]];
  }
  #pragma unroll
  for (int pt = 0; pt < 4; ++pt)
    #pragma unroll
    for (int r = 0; r < 16; ++r)
      out[((size_t)b * 128 + orows[r]) * N_ + n0 + pt * 32 + l31] = acc[pt][r] + bias[r];
}

// ---------------------------------------------------------------------------
extern "C" void kernel_launch(void* const* d_in, const int* in_sizes, int n_in,
                              void* d_out, int out_size, void* d_ws, size_t ws_size,
                              hipStream_t stream)
{
  const float* x     = (const float*)d_in[0];
  const float* qw    = (const float*)d_in[1];
  const float* qb    = (const float*)d_in[2];
  const float* kw    = (const float*)d_in[3];
  const float* kb    = (const float*)d_in[4];
  const float* vw    = (const float*)d_in[5];
  const float* vb    = (const float*)d_in[6];
  const float* ow    = (const float*)d_in[7];
  const float* ob    = (const float*)d_in[8];  (void)ob;
  const float* gamma = (const float*)d_in[9];
  const float* beta  = (const float*)d_in[10];
  float* out = (float*)d_out;
  float* ws  = (float*)d_ws;

  _Float16* q    = (_Float16*)(ws + OFF_QA);
  _Float16* k    = (_Float16*)(ws + OFF_K);
  _Float16* vT   = (_Float16*)(ws + OFF_VT);
  _Float16* aT   = (_Float16*)(ws + OFF_AT);
  _Float16* xT   = (_Float16*)(ws + OFF_XT);
  float* rope2   = ws + OFF_ROPE;
  _Float16* WB   = (_Float16*)(ws + OFF_WB);
  float* invf    = ws + OFF_INVF;
  _Float16* w2h  = (_Float16*)(ws + OFF_W2H);
  float* b2      = ws + OFF_B2;
  float* meanp   = ws + OFF_MEANP;
  float* Sp      = ws + OFF_SP;
  float* mean    = ws + OFF_MEAN;
  float* S       = ws + OFF_S;

  invf_kernel<<<1, 64, 0, stream>>>(invf);
  rope2_kernel<<<(N_ * 64) / 256, 256, 0, stream>>>(invf, rope2);
  prepack_kernel<<<dim3(128, 5, 3), 128, 0, stream>>>(qw, kw, vw, WB);
  xpose_kernel<<<dim3(N_ / 64, B_), 256, 0, stream>>>(x, xT);

  conv_kernel<<<dim3(N_ / 256, B_), 512, 0, stream>>>(xT, WB, qb, kb, vb, q, k, vT);

  attn_kernel<<<dim3(N_ / 128, B_), 512, 0, stream>>>(q, k, vT, rope2,
                                                      q /* a aliases q */, aT);

  stats_kernel<<<256, 256, 0, stream>>>(aT, Sp, meanp);
  reduce_kernel<<<64, 256, 0, stream>>>(Sp, meanp, S, mean);
  fold_kernel<<<128, 128, 0, stream>>>(S, mean, ow, gamma, beta, w2h, b2);

  out_kernel<<<dim3(N_ / 128, B_), 256, 0, stream>>>(q, w2h, b2, out);
}